// Round 5
// baseline (144.129 us; speedup 1.0000x reference)
//
#include <hip/hip_runtime.h>
#include <math.h>

namespace {

constexpr int K_ = 4;
constexpr int T_ = 1024;
constexpr int B_ = 2;
constexpr int D_ = 256;

constexpr int CH = 128;              // fine time chunks
constexpr int L_ = T_ / CH;          // 8 steps per chunk
constexpr int LOG_CH = 7;
constexpr int NG = 4;                // gather groups per block
constexpr int JPG = CH / NG;         // 32 chunks per group
constexpr unsigned MAGIC = 0x9E3779B1u;
constexpr int SPIN_MAX = 2000;       // bounded spin -> local recompute fallback

// ---------------------------------------------------------------------------
// Compile-time-foldable constants: Abar, Bbar (bilinear LegT, N=4, theta=200)
// exactly as the reference builds them (all-double Gauss-Jordan -> float).
// ---------------------------------------------------------------------------
__device__ __forceinline__ void base_consts(float Af[4][4], float Bf[4]) {
    const double dt = 1.0 / 200.0;
    double P[4], A[4][4];
#pragma unroll
    for (int n = 0; n < 4; ++n) P[n] = sqrt(2.0 * n + 1.0);
#pragma unroll
    for (int n = 0; n < 4; ++n)
#pragma unroll
        for (int k = 0; k < 4; ++k) {
            double s = (n >= k) ? 1.0 : (((k - n) & 1) ? -1.0 : 1.0);
            A[n][k] = -P[n] * P[k] * s;
        }
    double aug[4][9];
#pragma unroll
    for (int r = 0; r < 4; ++r) {
#pragma unroll
        for (int c = 0; c < 4; ++c) {
            double idc = (r == c) ? 1.0 : 0.0;
            aug[r][c]     = idc - 0.5 * dt * A[r][c];
            aug[r][4 + c] = idc + 0.5 * dt * A[r][c];
        }
        aug[r][8] = P[r] * dt;
    }
#pragma unroll
    for (int p = 0; p < 4; ++p) {
        double pinv = 1.0 / aug[p][p];
#pragma unroll
        for (int c = 0; c < 9; ++c) aug[p][c] *= pinv;
#pragma unroll
        for (int r = 0; r < 4; ++r) {
            if (r == p) continue;
            double f = aug[r][p];
#pragma unroll
            for (int c = 0; c < 9; ++c) aug[r][c] -= f * aug[p][c];
        }
    }
#pragma unroll
    for (int r = 0; r < 4; ++r) {
#pragma unroll
        for (int c = 0; c < 4; ++c) Af[r][c] = (float)aug[r][4 + c];
        Bf[r] = (float)aug[r][8];
    }
}

__device__ __forceinline__ void matsq(const float X[4][4], float Y[4][4]) {
#pragma unroll
    for (int r = 0; r < 4; ++r)
#pragma unroll
        for (int c = 0; c < 4; ++c) {
            float acc = 0.f;
#pragma unroll
            for (int k = 0; k < 4; ++k) acc = fmaf(X[r][k], X[k][c], acc);
            Y[r][c] = acc;
        }
}

#define MAT_APPLY(Mx, i0, i1, i2, i3, o0, o1, o2, o3, s0, s1, s2, s3)          \
    {                                                                          \
        o0 = fmaf(Mx[0][0], i0, fmaf(Mx[0][1], i1, fmaf(Mx[0][2], i2, fmaf(Mx[0][3], i3, s0)))); \
        o1 = fmaf(Mx[1][0], i0, fmaf(Mx[1][1], i1, fmaf(Mx[1][2], i2, fmaf(Mx[1][3], i3, s1)))); \
        o2 = fmaf(Mx[2][0], i0, fmaf(Mx[2][1], i1, fmaf(Mx[2][2], i2, fmaf(Mx[2][3], i3, s2)))); \
        o3 = fmaf(Mx[3][0], i0, fmaf(Mx[3][1], i1, fmaf(Mx[3][2], i2, fmaf(Mx[3][3], i3, s3)))); \
    }

// ===========================================================================
// Single-launch depth-1 decoupled scan, minimal producer work.
//
// Grid = B*CH = 256 blocks (<= CU count -> all resident) x 1024 threads
// (16 waves/CU), split as w = tid>>8 in 0..3 (gather group), d = tid&255.
//
//  publish: group 0 computes y_c[d] = sum_i M[7-i]*h[c*8+i,d] (8 coalesced
//           loads, the ONLY h reads) and publishes it via agent-scope
//           atomic stores + release flag.  All 256 producers run in
//           parallel -> flags all set ~1.3 us after launch, no serial chain.
//  gather:  group w Horner-combines y_j over j in [32w, min(c,32w+32))
//           with A8 = Abar^8 (compile-time), using 8-deep double-buffered
//           batched atomic loads (hides ~700cy coherent-load latency).
//           Partial scaled by A8^(c-hi_w) via bit-decomposed constant
//           matrices (round-3-verified algebra), merged through LDS.
//  emit:    group 0 runs the 8-step recurrence for chunk c (verified k2
//           math) and writes out with nontemporal stores.
//
// Bounded spin + cheap (8-load) local recompute fallback -> deadlock-free.
// ===========================================================================
__global__ __launch_bounds__(1024, 4) void hippo_lb(
    const float* __restrict__ h, const float* __restrict__ M,
    float* __restrict__ out, float* __restrict__ Pbuf,
    unsigned* __restrict__ flags)
{
    const int tid = threadIdx.x;
    const int d   = tid & (D_ - 1);
    const int w   = tid >> 8;                // 0..3
    const int c   = blockIdx.x & (CH - 1);
    const int b   = blockIdx.x >> LOG_CH;

    // ---- constants (compile-time foldable) ----
    float Af[4][4], Bf[4];
    base_consts(Af, Bf);
    float A8p[LOG_CH][4][4];                 // A8p[s] = (Abar^8)^(2^s)
    {
        float t2[4][4], t4[4][4];
        matsq(Af, t2);
        matsq(t2, t4);
        matsq(t4, A8p[0]);
#pragma unroll
        for (int s = 1; s < LOG_CH; ++s) matsq(A8p[s - 1], A8p[s]);
    }

    const float* hb = h + (size_t)b * (T_ * D_) + d;

    __shared__ unsigned missLds[NG];
    __shared__ float xs[NG][K_][D_];         // 16 KiB partial-merge buffer
    if (tid < NG) missLds[tid] = 0u;

    // ---- publish own chunk-sum y_c (group 0 only; 8 coalesced h loads) ----
    float ho[L_];
    if (w == 0) {
        float y0 = 0.f, y1 = 0.f, y2 = 0.f, y3 = 0.f;
#pragma unroll
        for (int i = 0; i < L_; ++i) {
            ho[i] = hb[((size_t)(c * L_ + i)) * D_];
            const float4 mr = ((const float4*)M)[L_ - 1 - i];
            y0 = fmaf(mr.x, ho[i], y0);
            y1 = fmaf(mr.y, ho[i], y1);
            y2 = fmaf(mr.z, ho[i], y2);
            y3 = fmaf(mr.w, ho[i], y3);
        }
        const size_t pb = ((size_t)(b * CH + c) * K_) * D_ + d;
        __hip_atomic_store(&Pbuf[pb + 0 * D_], y0, __ATOMIC_RELAXED, __HIP_MEMORY_SCOPE_AGENT);
        __hip_atomic_store(&Pbuf[pb + 1 * D_], y1, __ATOMIC_RELAXED, __HIP_MEMORY_SCOPE_AGENT);
        __hip_atomic_store(&Pbuf[pb + 2 * D_], y2, __ATOMIC_RELAXED, __HIP_MEMORY_SCOPE_AGENT);
        __hip_atomic_store(&Pbuf[pb + 3 * D_], y3, __ATOMIC_RELAXED, __HIP_MEMORY_SCOPE_AGENT);
    }
    __threadfence();
    __syncthreads();                          // all y-stores drained
    if (tid == 0)
        __hip_atomic_store(&flags[b * CH + c], MAGIC,
                           __ATOMIC_RELEASE, __HIP_MEMORY_SCOPE_AGENT);

    // ---- poll predecessor flags for this group's j-range ----
    const int lo  = w * JPG;
    const int hi  = (c < lo + JPG) ? c : (lo + JPG);   // empty if lo >= c
    const int njs = hi - lo;
    if (d < njs) {
        int spins = 0;
        while (__hip_atomic_load(&flags[b * CH + lo + d],
                                 __ATOMIC_ACQUIRE, __HIP_MEMORY_SCOPE_AGENT) != MAGIC) {
            if (++spins > SPIN_MAX) { atomicOr(&missLds[w], 1u << d); break; }
            __builtin_amdgcn_s_sleep(2);
        }
    }
    __syncthreads();
    const unsigned miss = missLds[w];

    // ---- batched gather (8-deep double-buffered) + Horner with A8 ----
    float cur[8][4], nxt[8][4];

    auto loadB = [&](int base, float (&buf)[8][4]) {
#pragma unroll
        for (int u = 0; u < 8; ++u) {
            const int j = base + u;
            if (j < hi) {                     // block-uniform predicate
                if (miss & (1u << (j - lo))) {
                    // fallback: recompute y_j from h (8 coalesced loads)
                    float a0 = 0.f, a1 = 0.f, a2 = 0.f, a3 = 0.f;
#pragma unroll
                    for (int i = 0; i < L_; ++i) {
                        const float hv = hb[((size_t)(j * L_ + i)) * D_];
                        const float4 mr = ((const float4*)M)[L_ - 1 - i];
                        a0 = fmaf(mr.x, hv, a0);
                        a1 = fmaf(mr.y, hv, a1);
                        a2 = fmaf(mr.z, hv, a2);
                        a3 = fmaf(mr.w, hv, a3);
                    }
                    buf[u][0] = a0; buf[u][1] = a1; buf[u][2] = a2; buf[u][3] = a3;
                } else {
                    const size_t pb = ((size_t)(b * CH + j) * K_) * D_ + d;
                    buf[u][0] = __hip_atomic_load(&Pbuf[pb + 0 * D_], __ATOMIC_RELAXED, __HIP_MEMORY_SCOPE_AGENT);
                    buf[u][1] = __hip_atomic_load(&Pbuf[pb + 1 * D_], __ATOMIC_RELAXED, __HIP_MEMORY_SCOPE_AGENT);
                    buf[u][2] = __hip_atomic_load(&Pbuf[pb + 2 * D_], __ATOMIC_RELAXED, __HIP_MEMORY_SCOPE_AGENT);
                    buf[u][3] = __hip_atomic_load(&Pbuf[pb + 3 * D_], __ATOMIC_RELAXED, __HIP_MEMORY_SCOPE_AGENT);
                }
            }
        }
    };

    float X0 = 0.f, X1 = 0.f, X2 = 0.f, X3 = 0.f;
    if (lo < hi) {
        loadB(lo, cur);
        for (int bs = lo; bs < hi; bs += 8) {
            loadB(bs + 8, nxt);               // next batch in flight
#pragma unroll
            for (int u = 0; u < 8; ++u) {
                if (bs + u < hi) {            // block-uniform
                    float n0, n1, n2, n3;
                    MAT_APPLY(A8p[0], X0, X1, X2, X3, n0, n1, n2, n3,
                              cur[u][0], cur[u][1], cur[u][2], cur[u][3]);
                    X0 = n0; X1 = n1; X2 = n2; X3 = n3;
                }
            }
#pragma unroll
            for (int u = 0; u < 8; ++u) {
                cur[u][0] = nxt[u][0]; cur[u][1] = nxt[u][1];
                cur[u][2] = nxt[u][2]; cur[u][3] = nxt[u][3];
            }
        }
        // scale partial by A8^(c - hi) (block-uniform exponent, <= 96)
        const int kexp = c - hi;
#pragma unroll
        for (int s = 0; s < LOG_CH; ++s) {
            if ((kexp >> s) & 1) {
                float t0, t1, t2, t3;
                MAT_APPLY(A8p[s], X0, X1, X2, X3, t0, t1, t2, t3,
                          0.f, 0.f, 0.f, 0.f);
                X0 = t0; X1 = t1; X2 = t2; X3 = t3;
            }
        }
    }

    // ---- merge the 4 group partials via LDS ----
    xs[w][0][d] = X0; xs[w][1][d] = X1; xs[w][2][d] = X2; xs[w][3][d] = X3;
    __syncthreads();

    if (w == 0) {
        float s0 = (xs[0][0][d] + xs[1][0][d]) + (xs[2][0][d] + xs[3][0][d]);
        float s1 = (xs[0][1][d] + xs[1][1][d]) + (xs[2][1][d] + xs[3][1][d]);
        float s2 = (xs[0][2][d] + xs[1][2][d]) + (xs[2][2][d] + xs[3][2][d]);
        float s3 = (xs[0][3][d] + xs[1][3][d]) + (xs[2][3][d] + xs[3][3][d]);

        // ---- emission for chunk c (identical math to verified k2_emit) ----
        float* op = out + ((size_t)(b * T_ + c * L_)) * (K_ * D_) + d;
#pragma unroll
        for (int i = 0; i < L_; ++i) {
            const float hv = ho[i];
            float n0, n1, n2, n3;
            MAT_APPLY(Af, s0, s1, s2, s3, n0, n1, n2, n3,
                      Bf[0] * hv, Bf[1] * hv, Bf[2] * hv, Bf[3] * hv);
            s0 = n0; s1 = n1; s2 = n2; s3 = n3;
            __builtin_nontemporal_store(s0, &op[0 * D_]);
            __builtin_nontemporal_store(s1, &op[1 * D_]);
            __builtin_nontemporal_store(s2, &op[2 * D_]);
            __builtin_nontemporal_store(s3, &op[3 * D_]);
            op += K_ * D_;
        }
    }
}

} // namespace

extern "C" void kernel_launch(void* const* d_in, const int* in_sizes, int n_in,
                              void* d_out, int out_size, void* d_ws, size_t ws_size,
                              hipStream_t stream) {
    const float* h = (const float*)d_in[0];   // (B, T, D) fp32
    const float* M = (const float*)d_in[1];   // (T, K)    fp32
    float* out = (float*)d_out;               // (B, T, K, D) fp32

    // ws layout: Pbuf [B][CH][K][D] floats = 1 MiB, then flags [B][CH] u32.
    float* Pbuf = (float*)d_ws;
    unsigned* flags = (unsigned*)((char*)d_ws + (size_t)B_ * CH * K_ * D_ * 4);

    hippo_lb<<<B_ * CH, NG * D_, 0, stream>>>(h, M, out, Pbuf, flags);
}

// Round 6
// 65.523 us; speedup vs baseline: 2.1997x; 2.1997x over previous
//
#include <hip/hip_runtime.h>
#include <math.h>

namespace {

constexpr int K_ = 4;
constexpr int T_ = 1024;
constexpr int B_ = 2;
constexpr int D_ = 256;

constexpr int CH = 128;              // fine time chunks
constexpr int L_ = T_ / CH;          // 8 steps per chunk
constexpr int LOG_CH = 7;
constexpr int ND = 8;                // d-columns per block
constexpr int NBLK = B_ * (D_ / ND); // 64 blocks, 1024 threads each

// ---------------------------------------------------------------------------
// Compile-time-foldable constants: Abar, Bbar (bilinear LegT, N=4, theta=200)
// exactly as the reference builds them (all-double Gauss-Jordan -> float).
// Verified numerics: identical to rounds 0-5 (absmax 9.77e-4).
// ---------------------------------------------------------------------------
__device__ __forceinline__ void base_consts(float Af[4][4], float Bf[4]) {
    const double dt = 1.0 / 200.0;
    double P[4], A[4][4];
#pragma unroll
    for (int n = 0; n < 4; ++n) P[n] = sqrt(2.0 * n + 1.0);
#pragma unroll
    for (int n = 0; n < 4; ++n)
#pragma unroll
        for (int k = 0; k < 4; ++k) {
            double s = (n >= k) ? 1.0 : (((k - n) & 1) ? -1.0 : 1.0);
            A[n][k] = -P[n] * P[k] * s;
        }
    double aug[4][9];
#pragma unroll
    for (int r = 0; r < 4; ++r) {
#pragma unroll
        for (int c = 0; c < 4; ++c) {
            double idc = (r == c) ? 1.0 : 0.0;
            aug[r][c]     = idc - 0.5 * dt * A[r][c];
            aug[r][4 + c] = idc + 0.5 * dt * A[r][c];
        }
        aug[r][8] = P[r] * dt;
    }
#pragma unroll
    for (int p = 0; p < 4; ++p) {
        double pinv = 1.0 / aug[p][p];
#pragma unroll
        for (int c = 0; c < 9; ++c) aug[p][c] *= pinv;
#pragma unroll
        for (int r = 0; r < 4; ++r) {
            if (r == p) continue;
            double f = aug[r][p];
#pragma unroll
            for (int c = 0; c < 9; ++c) aug[r][c] -= f * aug[p][c];
        }
    }
#pragma unroll
    for (int r = 0; r < 4; ++r) {
#pragma unroll
        for (int c = 0; c < 4; ++c) Af[r][c] = (float)aug[r][4 + c];
        Bf[r] = (float)aug[r][8];
    }
}

__device__ __forceinline__ void matsq(const float X[4][4], float Y[4][4]) {
#pragma unroll
    for (int r = 0; r < 4; ++r)
#pragma unroll
        for (int c = 0; c < 4; ++c) {
            float acc = 0.f;
#pragma unroll
            for (int k = 0; k < 4; ++k) acc = fmaf(X[r][k], X[k][c], acc);
            Y[r][c] = acc;
        }
}

// AP[s] = Abar^(8 * 2^s), s = 0..LOG_CH-1  (identical to verified k1b)
__device__ __forceinline__ void scan_consts(float AP[LOG_CH][4][4]) {
    float Af[4][4], Bf[4];
    base_consts(Af, Bf);
    float X[4][4], Y[4][4];
    matsq(Af, X);      // A^2
    matsq(X, Y);       // A^4
    matsq(Y, X);       // A^8
#pragma unroll
    for (int s = 0; s < LOG_CH; ++s) {
#pragma unroll
        for (int r = 0; r < 4; ++r)
#pragma unroll
            for (int c = 0; c < 4; ++c) AP[s][r][c] = X[r][c];
        matsq(X, Y);
#pragma unroll
        for (int r = 0; r < 4; ++r)
#pragma unroll
            for (int c = 0; c < 4; ++c) X[r][c] = Y[r][c];
    }
}

// ===========================================================================
// Single kernel, single launch, NO cross-block dependencies.
//
// Block = (b, d-group of 8 consecutive d) -> owns ALL 128 chunks of its 8
// sequences.  1024 threads: c = tid>>3 (chunk), s8 = tid&7 (d-sub).
// Grid = 64 blocks.
//
//  phase A (= verified k1a math): thread (c,s8) loads its chunk's 8 h rows
//          into registers (kept for emission) and computes the chunk-local
//          end state y_c = sum_i M[7-i]*h[8c+i].
//          Wave = 8 chunks x 8 d: each load instr = 8 aligned 32B segments.
//  phase B (= verified k1b body, ND=8 instead of 2): Kogge-Stone over the
//          128 chunks in LDS (7 steps, constant AP[s] matrices), then an
//          exclusive shift (lds[tid-8]) to get the chunk-start state.
//  phase C (= verified k2 math): 8-step recurrence with Af/Bf on the
//          registered h rows; nontemporal stores of (K=4) outputs.
//
// All coupling is intra-block __syncthreads(); h is read from HBM exactly
// once; workspace unused.
// ===========================================================================
__global__ __launch_bounds__(1024) void hippo_v6(
    const float* __restrict__ h, const float* __restrict__ M,
    float* __restrict__ out)
{
    const int tid = threadIdx.x;
    const int c   = tid >> 3;                 // 0..127
    const int s8  = tid & (ND - 1);           // 0..7
    const int b   = blockIdx.x >> 5;          // 0..1
    const int d   = (blockIdx.x & 31) * ND + s8;

    // ---- constants (compile-time foldable) ----
    float Af[4][4], Bf[4];
    base_consts(Af, Bf);
    float AP[LOG_CH][4][4];
    scan_consts(AP);

    // ---- phase A: load own chunk rows + chunk-local end state ----
    const float* hp = h + ((size_t)(b * T_ + c * L_)) * D_ + d;
    float ho[L_];
    float y0 = 0.f, y1 = 0.f, y2 = 0.f, y3 = 0.f;
#pragma unroll
    for (int i = 0; i < L_; ++i) {
        ho[i] = hp[i * D_];
        const float* mr = M + (L_ - 1 - i) * K_;   // uniform -> s_load
        y0 = fmaf(mr[0], ho[i], y0);
        y1 = fmaf(mr[1], ho[i], y1);
        y2 = fmaf(mr[2], ho[i], y2);
        y3 = fmaf(mr[3], ho[i], y3);
    }
    float4 v = make_float4(y0, y1, y2, y3);

    // ---- phase B: Kogge-Stone scan across 128 chunks (verified body) ----
    __shared__ float4 lds[CH * ND];           // 16 KiB
#pragma unroll
    for (int s = 0; s < LOG_CH; ++s) {
        const int off = 1 << s;
        lds[tid] = v;
        __syncthreads();
        if (c >= off) {
            float4 p = lds[tid - off * ND];
            v.x = fmaf(AP[s][0][0], p.x, fmaf(AP[s][0][1], p.y, fmaf(AP[s][0][2], p.z, fmaf(AP[s][0][3], p.w, v.x))));
            v.y = fmaf(AP[s][1][0], p.x, fmaf(AP[s][1][1], p.y, fmaf(AP[s][1][2], p.z, fmaf(AP[s][1][3], p.w, v.y))));
            v.z = fmaf(AP[s][2][0], p.x, fmaf(AP[s][2][1], p.y, fmaf(AP[s][2][2], p.z, fmaf(AP[s][2][3], p.w, v.z))));
            v.w = fmaf(AP[s][3][0], p.x, fmaf(AP[s][3][1], p.y, fmaf(AP[s][3][2], p.z, fmaf(AP[s][3][3], p.w, v.w))));
        }
        __syncthreads();
    }
    // exclusive shift: chunk-start state = inclusive state of chunk c-1
    lds[tid] = v;
    __syncthreads();
    float x0 = 0.f, x1 = 0.f, x2 = 0.f, x3 = 0.f;
    if (c > 0) {
        const float4 xi = lds[tid - ND];
        x0 = xi.x; x1 = xi.y; x2 = xi.z; x3 = xi.w;
    }

    // ---- phase C: emission for chunk c (verified k2 math) ----
    float* op = out + ((size_t)(b * T_ + c * L_)) * (K_ * D_) + d;
#pragma unroll
    for (int i = 0; i < L_; ++i) {
        const float hv = ho[i];
        const float n0 = fmaf(Af[0][0], x0, fmaf(Af[0][1], x1, fmaf(Af[0][2], x2, fmaf(Af[0][3], x3, Bf[0] * hv))));
        const float n1 = fmaf(Af[1][0], x0, fmaf(Af[1][1], x1, fmaf(Af[1][2], x2, fmaf(Af[1][3], x3, Bf[1] * hv))));
        const float n2 = fmaf(Af[2][0], x0, fmaf(Af[2][1], x1, fmaf(Af[2][2], x2, fmaf(Af[2][3], x3, Bf[2] * hv))));
        const float n3 = fmaf(Af[3][0], x0, fmaf(Af[3][1], x1, fmaf(Af[3][2], x2, fmaf(Af[3][3], x3, Bf[3] * hv))));
        x0 = n0; x1 = n1; x2 = n2; x3 = n3;
        __builtin_nontemporal_store(x0, &op[0 * D_]);
        __builtin_nontemporal_store(x1, &op[1 * D_]);
        __builtin_nontemporal_store(x2, &op[2 * D_]);
        __builtin_nontemporal_store(x3, &op[3 * D_]);
        op += K_ * D_;
    }
}

} // namespace

extern "C" void kernel_launch(void* const* d_in, const int* in_sizes, int n_in,
                              void* d_out, int out_size, void* d_ws, size_t ws_size,
                              hipStream_t stream) {
    const float* h = (const float*)d_in[0];   // (B, T, D) fp32
    const float* M = (const float*)d_in[1];   // (T, K)    fp32
    float* out = (float*)d_out;               // (B, T, K, D) fp32
    (void)d_ws; (void)ws_size;                // workspace unused

    hippo_v6<<<NBLK, CH * ND, 0, stream>>>(h, M, out);
}

// Round 7
// 63.858 us; speedup vs baseline: 2.2570x; 1.0261x over previous
//
#include <hip/hip_runtime.h>
#include <math.h>

namespace {

constexpr int K_ = 4;
constexpr int T_ = 1024;
constexpr int B_ = 2;
constexpr int D_ = 256;
constexpr int NSEQ = B_ * D_;        // 512 independent (b,d) sequences

constexpr int CH = 128;              // fine time chunks
constexpr int L_ = T_ / CH;          // 8 steps per chunk
constexpr int LOG_CH = 7;

// ---------------------------------------------------------------------------
// Compile-time-foldable constants: Abar, Bbar (bilinear LegT, N=4, theta=200)
// exactly as the reference builds them (all-double Gauss-Jordan -> float).
// ---------------------------------------------------------------------------
__device__ __forceinline__ void base_consts(float Af[4][4], float Bf[4]) {
    const double dt = 1.0 / 200.0;
    double P[4], A[4][4];
#pragma unroll
    for (int n = 0; n < 4; ++n) P[n] = sqrt(2.0 * n + 1.0);
#pragma unroll
    for (int n = 0; n < 4; ++n)
#pragma unroll
        for (int k = 0; k < 4; ++k) {
            double s = (n >= k) ? 1.0 : (((k - n) & 1) ? -1.0 : 1.0);
            A[n][k] = -P[n] * P[k] * s;
        }
    double aug[4][9];
#pragma unroll
    for (int r = 0; r < 4; ++r) {
#pragma unroll
        for (int c = 0; c < 4; ++c) {
            double idc = (r == c) ? 1.0 : 0.0;
            aug[r][c]     = idc - 0.5 * dt * A[r][c];
            aug[r][4 + c] = idc + 0.5 * dt * A[r][c];
        }
        aug[r][8] = P[r] * dt;
    }
#pragma unroll
    for (int p = 0; p < 4; ++p) {
        double pinv = 1.0 / aug[p][p];
#pragma unroll
        for (int c = 0; c < 9; ++c) aug[p][c] *= pinv;
#pragma unroll
        for (int r = 0; r < 4; ++r) {
            if (r == p) continue;
            double f = aug[r][p];
#pragma unroll
            for (int c = 0; c < 9; ++c) aug[r][c] -= f * aug[p][c];
        }
    }
#pragma unroll
    for (int r = 0; r < 4; ++r) {
#pragma unroll
        for (int c = 0; c < 4; ++c) Af[r][c] = (float)aug[r][4 + c];
        Bf[r] = (float)aug[r][8];
    }
}

__device__ __forceinline__ void matsq(const float X[4][4], float Y[4][4]) {
#pragma unroll
    for (int r = 0; r < 4; ++r)
#pragma unroll
        for (int c = 0; c < 4; ++c) {
            float acc = 0.f;
#pragma unroll
            for (int k = 0; k < 4; ++k) acc = fmaf(X[r][k], X[k][c], acc);
            Y[r][c] = acc;
        }
}

// AP[s] = Abar^(8 * 2^s), s = 0..LOG_CH-1  (identical to verified k1b)
__device__ __forceinline__ void scan_consts(float AP[LOG_CH][4][4]) {
    float Af[4][4], Bf[4];
    base_consts(Af, Bf);
    float X[4][4], Y[4][4];
    matsq(Af, X);      // A^2
    matsq(X, Y);       // A^4
    matsq(Y, X);       // A^8
#pragma unroll
    for (int s = 0; s < LOG_CH; ++s) {
#pragma unroll
        for (int r = 0; r < 4; ++r)
#pragma unroll
            for (int c = 0; c < 4; ++c) AP[s][r][c] = X[r][c];
        matsq(X, Y);
#pragma unroll
        for (int r = 0; r < 4; ++r)
#pragma unroll
            for (int c = 0; c < 4; ++c) X[r][c] = Y[r][c];
    }
}

// ---------------------------------------------------------------------------
// k_scan = k1a fused into k1b: block = 128 chunks x 2 seqs, grid = NSEQ/2.
// Each thread computes its chunk-local end state directly from h (the old
// k1a math, verbatim FMA order), then Kogge-Stone scans across the 128
// chunks (old k1b body, verbatim), writing the EXCLUSIVE prefix to ws_init.
// Eliminates the k1a launch + the ws_y round trip.
// ---------------------------------------------------------------------------
__global__ __launch_bounds__(256) void k_scan(
    const float* __restrict__ h, const float* __restrict__ M,
    float* __restrict__ ws_init)
{
    const int sp = threadIdx.x & 1;
    const int c  = threadIdx.x >> 1;          // 0..127
    const int seq = blockIdx.x * 2 + sp;
    const int b = seq >> 8, d = seq & (D_ - 1);

    float AP[LOG_CH][4][4];
    scan_consts(AP);

    // chunk-local end state (old k1a body, same FMA order)
    const float* hp = h + ((size_t)(b * T_ + c * L_)) * D_ + d;
    float y0 = 0.f, y1 = 0.f, y2 = 0.f, y3 = 0.f;
#pragma unroll
    for (int i = 0; i < L_; ++i) {
        float hv = hp[i * D_];
        const float* mr = M + (L_ - 1 - i) * K_;
        y0 = fmaf(mr[0], hv, y0);
        y1 = fmaf(mr[1], hv, y1);
        y2 = fmaf(mr[2], hv, y2);
        y3 = fmaf(mr[3], hv, y3);
    }
    float4 v = make_float4(y0, y1, y2, y3);

    // Kogge-Stone over 128 chunks (old k1b body, verbatim)
    __shared__ float4 lds[CH * 2];
#pragma unroll
    for (int s = 0; s < LOG_CH; ++s) {
        const int off = 1 << s;
        lds[threadIdx.x] = v;
        __syncthreads();
        if (c >= off) {
            float4 p = lds[threadIdx.x - off * 2];
            v.x = fmaf(AP[s][0][0], p.x, fmaf(AP[s][0][1], p.y, fmaf(AP[s][0][2], p.z, fmaf(AP[s][0][3], p.w, v.x))));
            v.y = fmaf(AP[s][1][0], p.x, fmaf(AP[s][1][1], p.y, fmaf(AP[s][1][2], p.z, fmaf(AP[s][1][3], p.w, v.y))));
            v.z = fmaf(AP[s][2][0], p.x, fmaf(AP[s][2][1], p.y, fmaf(AP[s][2][2], p.z, fmaf(AP[s][2][3], p.w, v.z))));
            v.w = fmaf(AP[s][3][0], p.x, fmaf(AP[s][3][1], p.y, fmaf(AP[s][3][2], p.z, fmaf(AP[s][3][3], p.w, v.w))));
        }
        __syncthreads();
    }
    // v = inclusive state after chunk c; init[c+1] = v, init[0] = 0
    float4* ip = (float4*)ws_init;
    if (c < CH - 1) ip[(size_t)(c + 1) * NSEQ + seq] = v;
    if (c == 0)     ip[seq] = make_float4(0.f, 0.f, 0.f, 0.f);
}

// ---------------------------------------------------------------------------
// k_emit = old k2_emit verbatim (256 blocks x 256 threads, 1KiB-coalesced
// loads/stores) + nontemporal output stores.
// ---------------------------------------------------------------------------
__global__ __launch_bounds__(256) void k_emit(
    const float* __restrict__ h, const float* __restrict__ ws_init,
    float* __restrict__ out)
{
    const int d = threadIdx.x;
    const int c = blockIdx.x & (CH - 1);
    const int b = blockIdx.x >> LOG_CH;

    float Af[4][4], Bf[4];
    base_consts(Af, Bf);

    float4 xi = ((const float4*)ws_init)[(size_t)c * NSEQ + b * D_ + d];
    float x0 = xi.x, x1 = xi.y, x2 = xi.z, x3 = xi.w;

    const float* hp = h + ((size_t)(b * T_ + c * L_)) * D_ + d;
    float* op = out + ((size_t)(b * T_ + c * L_)) * K_ * D_ + d;
#pragma unroll
    for (int i = 0; i < L_; ++i) {
        float hv = hp[i * D_];
        float n0 = fmaf(Af[0][0], x0, fmaf(Af[0][1], x1, fmaf(Af[0][2], x2, fmaf(Af[0][3], x3, Bf[0] * hv))));
        float n1 = fmaf(Af[1][0], x0, fmaf(Af[1][1], x1, fmaf(Af[1][2], x2, fmaf(Af[1][3], x3, Bf[1] * hv))));
        float n2 = fmaf(Af[2][0], x0, fmaf(Af[2][1], x1, fmaf(Af[2][2], x2, fmaf(Af[2][3], x3, Bf[2] * hv))));
        float n3 = fmaf(Af[3][0], x0, fmaf(Af[3][1], x1, fmaf(Af[3][2], x2, fmaf(Af[3][3], x3, Bf[3] * hv))));
        x0 = n0; x1 = n1; x2 = n2; x3 = n3;
        __builtin_nontemporal_store(x0, &op[0 * D_]);
        __builtin_nontemporal_store(x1, &op[1 * D_]);
        __builtin_nontemporal_store(x2, &op[2 * D_]);
        __builtin_nontemporal_store(x3, &op[3 * D_]);
        op += K_ * D_;
    }
}

} // namespace

extern "C" void kernel_launch(void* const* d_in, const int* in_sizes, int n_in,
                              void* d_out, int out_size, void* d_ws, size_t ws_size,
                              hipStream_t stream) {
    const float* h = (const float*)d_in[0];   // (B, T, D) fp32
    const float* M = (const float*)d_in[1];   // (T, K)    fp32
    float* out = (float*)d_out;               // (B, T, K, D) fp32

    // ws layout: init[CH][NSEQ][4]  (1 MiB)
    float* ws_init = (float*)d_ws;

    k_scan<<<NSEQ / 2, 256, 0, stream>>>(h, M, ws_init);
    k_emit<<<B_ * CH, 256, 0, stream>>>(h, ws_init, out);
}

// Round 8
// 63.157 us; speedup vs baseline: 2.2821x; 1.0111x over previous
//
#include <hip/hip_runtime.h>
#include <math.h>

namespace {

constexpr int K_ = 4;
constexpr int T_ = 1024;
constexpr int B_ = 2;
constexpr int D_ = 256;
constexpr int NSEQ = B_ * D_;        // 512 independent (b,d) sequences

constexpr int CH = 128;              // fine time chunks
constexpr int L_ = T_ / CH;          // 8 steps per chunk
constexpr int LOG_CH = 7;
constexpr int NPAIR = CH / 2;        // 64 chunk-pairs
constexpr int SD = 16;               // d-columns per scan block (64B line)

// ---------------------------------------------------------------------------
// Compile-time-foldable constants: Abar, Bbar (bilinear LegT, N=4, theta=200)
// exactly as the reference builds them (all-double Gauss-Jordan -> float).
// ---------------------------------------------------------------------------
__device__ __forceinline__ void base_consts(float Af[4][4], float Bf[4]) {
    const double dt = 1.0 / 200.0;
    double P[4], A[4][4];
#pragma unroll
    for (int n = 0; n < 4; ++n) P[n] = sqrt(2.0 * n + 1.0);
#pragma unroll
    for (int n = 0; n < 4; ++n)
#pragma unroll
        for (int k = 0; k < 4; ++k) {
            double s = (n >= k) ? 1.0 : (((k - n) & 1) ? -1.0 : 1.0);
            A[n][k] = -P[n] * P[k] * s;
        }
    double aug[4][9];
#pragma unroll
    for (int r = 0; r < 4; ++r) {
#pragma unroll
        for (int c = 0; c < 4; ++c) {
            double idc = (r == c) ? 1.0 : 0.0;
            aug[r][c]     = idc - 0.5 * dt * A[r][c];
            aug[r][4 + c] = idc + 0.5 * dt * A[r][c];
        }
        aug[r][8] = P[r] * dt;
    }
#pragma unroll
    for (int p = 0; p < 4; ++p) {
        double pinv = 1.0 / aug[p][p];
#pragma unroll
        for (int c = 0; c < 9; ++c) aug[p][c] *= pinv;
#pragma unroll
        for (int r = 0; r < 4; ++r) {
            if (r == p) continue;
            double f = aug[r][p];
#pragma unroll
            for (int c = 0; c < 9; ++c) aug[r][c] -= f * aug[p][c];
        }
    }
#pragma unroll
    for (int r = 0; r < 4; ++r) {
#pragma unroll
        for (int c = 0; c < 4; ++c) Af[r][c] = (float)aug[r][4 + c];
        Bf[r] = (float)aug[r][8];
    }
}

__device__ __forceinline__ void matsq(const float X[4][4], float Y[4][4]) {
#pragma unroll
    for (int r = 0; r < 4; ++r)
#pragma unroll
        for (int c = 0; c < 4; ++c) {
            float acc = 0.f;
#pragma unroll
            for (int k = 0; k < 4; ++k) acc = fmaf(X[r][k], X[k][c], acc);
            Y[r][c] = acc;
        }
}

// AP[s] = Abar^(8 * 2^s), s = 0..LOG_CH-1
__device__ __forceinline__ void scan_consts(float AP[LOG_CH][4][4]) {
    float Af[4][4], Bf[4];
    base_consts(Af, Bf);
    float X[4][4], Y[4][4];
    matsq(Af, X);      // A^2
    matsq(X, Y);       // A^4
    matsq(Y, X);       // A^8
#pragma unroll
    for (int s = 0; s < LOG_CH; ++s) {
#pragma unroll
        for (int r = 0; r < 4; ++r)
#pragma unroll
            for (int c = 0; c < 4; ++c) AP[s][r][c] = X[r][c];
        matsq(X, Y);
#pragma unroll
        for (int r = 0; r < 4; ++r)
#pragma unroll
            for (int c = 0; c < 4; ++c) X[r][c] = Y[r][c];
    }
}

#define MAT_AFF(Mx, i0, i1, i2, i3, o0, o1, o2, o3, s0, s1, s2, s3)            \
    {                                                                          \
        o0 = fmaf(Mx[0][0], i0, fmaf(Mx[0][1], i1, fmaf(Mx[0][2], i2, fmaf(Mx[0][3], i3, s0)))); \
        o1 = fmaf(Mx[1][0], i0, fmaf(Mx[1][1], i1, fmaf(Mx[1][2], i2, fmaf(Mx[1][3], i3, s1)))); \
        o2 = fmaf(Mx[2][0], i0, fmaf(Mx[2][1], i1, fmaf(Mx[2][2], i2, fmaf(Mx[2][3], i3, s2)))); \
        o3 = fmaf(Mx[3][0], i0, fmaf(Mx[3][1], i1, fmaf(Mx[3][2], i2, fmaf(Mx[3][3], i3, s3)))); \
    }

// ---------------------------------------------------------------------------
// k_scan v2: fully-coalesced chunk-sum + pair-level Kogge-Stone.
//
// Block = 1024 threads: s16 = tid&15 (d-sub, 64B line), c2 = tid>>4
// (chunk-pair 0..63).  Grid = NSEQ/16 = 32 blocks (16 waves/CU).
//
//  A: thread folds its 2 chunks from 16 coalesced h rows (each wave load
//     instr = 4 fully-used 64B segments):  y_even, y_odd;
//     pair value v = A8*y_even + y_odd.
//  B: 6-step Kogge-Stone over 64 pairs with A16^(2^s) = AP[s+1].
//  C: exclusive inits: init[2c2] = prev (pair-exclusive), and
//     init[2c2+1] = A8*prev + y_even; written 256B-coalesced to ws_init.
// ---------------------------------------------------------------------------
__global__ __launch_bounds__(1024) void k_scan(
    const float* __restrict__ h, const float* __restrict__ M,
    float* __restrict__ ws_init)
{
    const int tid  = threadIdx.x;
    const int s16  = tid & (SD - 1);
    const int c2   = tid >> 4;                 // 0..63
    const int b    = blockIdx.x >> 4;          // 16 blocks per batch
    const int d    = (blockIdx.x & 15) * SD + s16;
    const int seq  = b * D_ + d;

    float AP[LOG_CH][4][4];
    scan_consts(AP);

    // chunk-sum coefficients mc[i][k] = M[7-i][k] (uniform -> s_load)
    float mc[L_][K_];
#pragma unroll
    for (int i = 0; i < L_; ++i) {
        const float4 mr = ((const float4*)M)[L_ - 1 - i];
        mc[i][0] = mr.x; mc[i][1] = mr.y; mc[i][2] = mr.z; mc[i][3] = mr.w;
    }

    // ---- A: fold two chunks (16 coalesced rows) ----
    const float* hp = h + ((size_t)(b * T_ + c2 * 2 * L_)) * D_ + d;
    float e0 = 0.f, e1 = 0.f, e2 = 0.f, e3 = 0.f;   // y_even
    float o0 = 0.f, o1 = 0.f, o2 = 0.f, o3 = 0.f;   // y_odd
#pragma unroll
    for (int i = 0; i < L_; ++i) {
        const float hv = hp[i * D_];
        e0 = fmaf(mc[i][0], hv, e0);
        e1 = fmaf(mc[i][1], hv, e1);
        e2 = fmaf(mc[i][2], hv, e2);
        e3 = fmaf(mc[i][3], hv, e3);
    }
#pragma unroll
    for (int i = 0; i < L_; ++i) {
        const float hv = hp[(L_ + i) * D_];
        o0 = fmaf(mc[i][0], hv, o0);
        o1 = fmaf(mc[i][1], hv, o1);
        o2 = fmaf(mc[i][2], hv, o2);
        o3 = fmaf(mc[i][3], hv, o3);
    }
    // pair value v = A8 * y_even + y_odd   (A8 = AP[0])
    float4 v;
    MAT_AFF(AP[0], e0, e1, e2, e3, v.x, v.y, v.z, v.w, o0, o1, o2, o3);

    // ---- B: Kogge-Stone over 64 pairs, matrices A16^(2^s) = AP[s+1] ----
    __shared__ float4 lds[NPAIR * SD];         // 16 KiB, idx == tid
#pragma unroll
    for (int s = 0; s < 6; ++s) {
        const int off = 1 << s;
        lds[tid] = v;
        __syncthreads();
        if (c2 >= off) {
            const float4 p = lds[tid - off * SD];
            const float4 t = v;
            MAT_AFF(AP[s + 1], p.x, p.y, p.z, p.w, v.x, v.y, v.z, v.w,
                    t.x, t.y, t.z, t.w);
        }
        __syncthreads();
    }

    // ---- C: exclusive shift + per-chunk inits ----
    lds[tid] = v;
    __syncthreads();
    float q0 = 0.f, q1 = 0.f, q2 = 0.f, q3 = 0.f;  // init of chunk 2c2
    if (c2 > 0) {
        const float4 p = lds[tid - SD];
        q0 = p.x; q1 = p.y; q2 = p.z; q3 = p.w;
    }
    float r0, r1, r2, r3;                          // init of chunk 2c2+1
    MAT_AFF(AP[0], q0, q1, q2, q3, r0, r1, r2, r3, e0, e1, e2, e3);

    float4* ip = (float4*)ws_init;
    ip[(size_t)(2 * c2)     * NSEQ + seq] = make_float4(q0, q1, q2, q3);
    ip[(size_t)(2 * c2 + 1) * NSEQ + seq] = make_float4(r0, r1, r2, r3);
}

// ---------------------------------------------------------------------------
// k_emit = old k2_emit verbatim (256 blocks x 256 threads, 1KiB-coalesced
// loads/stores) + nontemporal output stores.  Unchanged from round 7.
// ---------------------------------------------------------------------------
__global__ __launch_bounds__(256) void k_emit(
    const float* __restrict__ h, const float* __restrict__ ws_init,
    float* __restrict__ out)
{
    const int d = threadIdx.x;
    const int c = blockIdx.x & (CH - 1);
    const int b = blockIdx.x >> LOG_CH;

    float Af[4][4], Bf[4];
    base_consts(Af, Bf);

    float4 xi = ((const float4*)ws_init)[(size_t)c * NSEQ + b * D_ + d];
    float x0 = xi.x, x1 = xi.y, x2 = xi.z, x3 = xi.w;

    const float* hp = h + ((size_t)(b * T_ + c * L_)) * D_ + d;
    float* op = out + ((size_t)(b * T_ + c * L_)) * K_ * D_ + d;
#pragma unroll
    for (int i = 0; i < L_; ++i) {
        float hv = hp[i * D_];
        float n0 = fmaf(Af[0][0], x0, fmaf(Af[0][1], x1, fmaf(Af[0][2], x2, fmaf(Af[0][3], x3, Bf[0] * hv))));
        float n1 = fmaf(Af[1][0], x0, fmaf(Af[1][1], x1, fmaf(Af[1][2], x2, fmaf(Af[1][3], x3, Bf[1] * hv))));
        float n2 = fmaf(Af[2][0], x0, fmaf(Af[2][1], x1, fmaf(Af[2][2], x2, fmaf(Af[2][3], x3, Bf[2] * hv))));
        float n3 = fmaf(Af[3][0], x0, fmaf(Af[3][1], x1, fmaf(Af[3][2], x2, fmaf(Af[3][3], x3, Bf[3] * hv))));
        x0 = n0; x1 = n1; x2 = n2; x3 = n3;
        __builtin_nontemporal_store(x0, &op[0 * D_]);
        __builtin_nontemporal_store(x1, &op[1 * D_]);
        __builtin_nontemporal_store(x2, &op[2 * D_]);
        __builtin_nontemporal_store(x3, &op[3 * D_]);
        op += K_ * D_;
    }
}

} // namespace

extern "C" void kernel_launch(void* const* d_in, const int* in_sizes, int n_in,
                              void* d_out, int out_size, void* d_ws, size_t ws_size,
                              hipStream_t stream) {
    const float* h = (const float*)d_in[0];   // (B, T, D) fp32
    const float* M = (const float*)d_in[1];   // (T, K)    fp32
    float* out = (float*)d_out;               // (B, T, K, D) fp32

    // ws layout: init[CH][NSEQ][4]  (1 MiB)
    float* ws_init = (float*)d_ws;

    k_scan<<<NSEQ / SD, NPAIR * SD, 0, stream>>>(h, M, ws_init);
    k_emit<<<B_ * CH, 256, 0, stream>>>(h, ws_init, out);
}